// Round 9
// baseline (194.366 us; speedup 1.0000x reference)
//
#include <hip/hip_runtime.h>
#include <hip/hip_bf16.h>
#include <stdint.h>

#define S_LEN 2048
#define NH 16
#define NB_DELTA (2*S_LEN-1)   // 4095
#define LOG2E 1.4426950408889634f

typedef __attribute__((ext_vector_type(8))) __bf16 bf16x8;
typedef __attribute__((ext_vector_type(4))) float f32x4;

__device__ __forceinline__ unsigned short f2bf(float f){   // RNE
    union { float f; unsigned int u; } v; v.f = f;
    unsigned int u = v.u;
    return (unsigned short)((u + 0x7FFFu + ((u >> 16) & 1u)) >> 16);
}
__device__ __forceinline__ float bf2f(unsigned short u){
    union { unsigned int u; float f; } v; v.u = ((unsigned int)u) << 16;
    return v.f;
}
__device__ __forceinline__ unsigned int pkbf(float a, float b){   // HW packed cvt (RNE)
    __hip_bfloat162 h = __float22bfloat162_rn(float2{a, b});
    unsigned int u;
    __builtin_memcpy(&u, &h, 4);
    return u;
}
#if __has_builtin(__builtin_amdgcn_exp2f)
__device__ __forceinline__ float fexp2(float x){ return __builtin_amdgcn_exp2f(x); }
#else
__device__ __forceinline__ float fexp2(float x){ return __expf(x * 0.69314718056f); }
#endif

// async global->LDS, 16B per lane; LDS dest = wave-uniform base + lane*16
__device__ __forceinline__ void gload16(const void* g, void* l){
    __builtin_amdgcn_global_load_lds(
        (const __attribute__((address_space(1))) void*)(uintptr_t)g,
        (__attribute__((address_space(3))) void*)(uintptr_t)l, 16, 0, 0);
}

// ---------------- fused prep: z<4 -> transpose+cast W[z]; z==4 -> hs cast + bias table
// biasT is PRE-SCALED: (bias - 16) * log2e  (exp2-softmax form; the -16 cancels in softmax)
__global__ __launch_bounds__(256) void prep_kernel(
    const float* __restrict__ hs, unsigned short* __restrict__ hsb,
    const float* __restrict__ W0, const float* __restrict__ W1,
    const float* __restrict__ W2, const float* __restrict__ W3,
    unsigned short* __restrict__ D0, unsigned short* __restrict__ D1,
    unsigned short* __restrict__ D2, unsigned short* __restrict__ D3,
    const float* __restrict__ rel_bias, float* __restrict__ biasT){
    if (blockIdx.z == 4) {
        int bi = blockIdx.y * 32 + blockIdx.x;   // 0..1023
        for (int it = 0; it < 4; it++) {
            int i = bi * 4096 + it * 1024 + threadIdx.x * 4;
            float4 f = *(const float4*)(hs + i);
            ushort4 o;
            o.x = f2bf(f.x); o.y = f2bf(f.y); o.z = f2bf(f.z); o.w = f2bf(f.w);
            *(ushort4*)(hsb + i) = o;
        }
        if (bi < 16) {
            int t = bi * 256 + threadIdx.x;
            if (t < NB_DELTA) {
                int delta = t - (S_LEN - 1);          // j - i
                int bucket = (delta > 0) ? 16 : 0;
                int a = delta < 0 ? -delta : delta;
                int b;
                if (a < 8) b = a;
                else {
                    int bl = 33 - __builtin_clz(a * a);   // 8 + floor(2*log2(a/8)), exact
                    b = bl < 15 ? bl : 15;
                }
                bucket += b;
                for (int h = 0; h < NH; h++)
                    biasT[h * NB_DELTA + t] = (rel_bias[bucket * NH + h] - 16.f) * LOG2E;
            }
        }
        return;
    }
    const float* src; unsigned short* dst;
    switch (blockIdx.z) {
        case 0: src = W0; dst = D0; break;
        case 1: src = W1; dst = D1; break;
        case 2: src = W2; dst = D2; break;
        default: src = W3; dst = D3; break;
    }
    __shared__ float tile[32][33];
    int bx = blockIdx.x, by = blockIdx.y;
    int tx = threadIdx.x & 31, ty = threadIdx.x >> 5;
    for (int i = 0; i < 4; i++)
        tile[ty + 8*i][tx] = src[(size_t)(by*32 + ty + 8*i) * 1024 + bx*32 + tx];
    __syncthreads();
    for (int i = 0; i < 4; i++)
        dst[(size_t)(bx*32 + ty + 8*i) * 1024 + by*32 + tx] = f2bf(tile[tx][ty + 8*i]);
}

// ---------------- bf16 MFMA GEMM, BK=64, async staging, XOR-granule-swizzled LDS.
// MODE 0: fp32 row-major into C0 (ldc).
// MODE 1: bf16 into C1 with stride ldc for cols<2048 (Q block pre-scaled by
//         log2e; Q|K packed at stride 2048); cols>=2048 (the V block) are
//         written TRANSPOSED into Vt[b*1024+v][s].
template<int MODE, int BM>
__global__ __launch_bounds__(256) void gemm_bt_kernel(const unsigned short* __restrict__ A,
                                                      const unsigned short* __restrict__ BT,
                                                      float* __restrict__ C0,
                                                      unsigned short* __restrict__ C1,
                                                      unsigned short* __restrict__ Vt,
                                                      int Kdim, int ldc){
    constexpr int IT = BM / 32;     // m-tiles per wave
    __shared__ __align__(16) unsigned short As[BM * 64];
    __shared__ __align__(16) unsigned short Bs[128 * 64];
    const int t = threadIdx.x;
    const int wave = t >> 6, lane = t & 63;
    const int quad = lane >> 4, l16 = lane & 15;
    const int wm = (wave >> 1) * (BM / 2), wn = (wave & 1) * 64;
    const size_t row0 = (size_t)blockIdx.y * BM, col0 = (size_t)blockIdx.x * 128;

    const int srow8 = lane >> 3;                 // 0..7: row within the wave's 8-row group
    const int gg = (lane & 7) ^ srow8;           // fetch-side granule remap
    const unsigned short* gA = A  + (row0 + wave * 8 + srow8) * (size_t)Kdim + gg * 8;
    const unsigned short* gB = BT + (col0 + wave * 8 + srow8) * (size_t)Kdim + gg * 8;

    f32x4 acc[IT][4] = {};

    for (int kt = 0; kt < Kdim; kt += 64) {
        for (int p = 0; p < BM / 32; p++)
            gload16(gA + (size_t)(p * 32) * Kdim + kt, &As[(p * 32 + wave * 8) * 64]);
        for (int p = 0; p < 4; p++)
            gload16(gB + (size_t)(p * 32) * Kdim + kt, &Bs[(p * 32 + wave * 8) * 64]);
        __syncthreads();
        bf16x8 a[2][IT], b[2][4];
        for (int ks = 0; ks < 2; ks++) {
            for (int i = 0; i < IT; i++)
                a[ks][i] = *(const bf16x8*)(&As[(wm + i*16 + l16) * 64 + (((ks*4 + quad) ^ (l16 & 7)) * 8)]);
            for (int j = 0; j < 4; j++)
                b[ks][j] = *(const bf16x8*)(&Bs[(wn + j*16 + l16) * 64 + (((ks*4 + quad) ^ (l16 & 7)) * 8)]);
        }
        for (int ks = 0; ks < 2; ks++)
            for (int i = 0; i < IT; i++)
                for (int j = 0; j < 4; j++)
                    acc[i][j] = __builtin_amdgcn_mfma_f32_16x16x32_bf16(a[ks][i], b[ks][j], acc[i][j], 0, 0, 0);
        __syncthreads();
    }
    // C/D layout: col = lane&15, row = quad*4 + reg
    for (int i = 0; i < IT; i++)
        for (int j = 0; j < 4; j++) {
            size_t r0 = row0 + wm + i*16 + quad*4;
            size_t c  = col0 + wn + j*16 + l16;
            if (MODE == 0) {
                for (int r = 0; r < 4; r++)
                    C0[(r0 + r) * ldc + c] = acc[i][j][r];
            } else if (c < 2048) {
                float qs = (c < 1024) ? LOG2E : 1.0f;   // pre-scale Q for exp2 softmax
                for (int r = 0; r < 4; r++)
                    C1[(r0 + r) * ldc + c] = f2bf(acc[i][j][r] * qs);
            } else {
                // V block: write transposed. rows r0..r0+3 are 4 consecutive s -> one 8B store.
                size_t bb = r0 >> 11, s = r0 & 2047;
                ushort4 o;
                o.x = f2bf(acc[i][j][0]); o.y = f2bf(acc[i][j][1]);
                o.z = f2bf(acc[i][j][2]); o.w = f2bf(acc[i][j][3]);
                *(ushort4*)(Vt + ((bb << 10) + (c - 2048)) * 2048 + s) = o;
            }
        }
}

// ---------------- MFMA flash attention v19: FULL-S, NO SPLIT.
// One block owns a 128-q tile for all 2048 j (32 k-tiles): the row sum is
// complete in-register at the epilogue, so the block normalizes and writes the
// FINAL bf16 ctx directly. Eliminates ctxpb partials (17MB W + 34MB R), rsbuf,
// and the combine/MODE2 machinery; gemm2 reverts to pure gload16 MODE0.
// Geometry: 256-thr blocks (4 waves x 32q -- the LDS-efficient wave shape),
// grid 16qt x 16h x 2b = 512 = 2 blocks/CU (two independent barrier domains).
// Keeps: double-buffered K/V prefetch, bias as MFMA C-init (scalar LDS table),
// nb-outer pipelined QK^T+exp2, in-register P via permlane32/16_swap, row sums
// via ones-row MFMA, chunked XCD swizzle.
__global__ __launch_bounds__(256, 2) void flash19_kernel(
    const unsigned short* __restrict__ qkb,   // [4096][2048] bf16: Q | K
    const unsigned short* __restrict__ vt,    // [2][1024][2048] bf16 V^T
    const float* __restrict__ biasT,          // pre-scaled (x-16)*log2e
    unsigned short* __restrict__ ctxb)        // [4096][1024] bf16 NORMALIZED
{
    // chunked XCD swizzle: the 16 qt-blocks sharing (h,b) sit in one
    // 64-chunk -> one XCD -> K/V panel fetched once per XCD.
    const int lin  = blockIdx.x;               // 0..511
    const int logi = (lin & 7) * 64 + (lin >> 3);
    const int qt = logi & 15, h = (logi >> 4) & 15;
    const int b = logi >> 8;
    const int t = threadIdx.x;
    const int w = t >> 6, lane = t & 63, quad = lane >> 4, l16 = lane & 15;
    const int q0 = qt * 128;

    __shared__ __align__(16) unsigned short Ks[2][64 * 64];   // [token j][dim], swizzled
    __shared__ __align__(16) unsigned short Vs[2][64 * 64];   // [dim d][token], swizzled
    __shared__ float bias_b[2304];   // deltas this block touches (u in [128, 2303))

    // bias table: u index = 255 + j - (qrow - q0) relative to base 1792 - q0.
    // u range [128, 2302]; global index base+u in [1792-q0+128, 1792-q0+2302],
    // always within [0, 4094] for q0 in [0, 1920].
    {
        const float* bsrc = biasT + h * NB_DELTA + (1792 - q0);
        for (int u = 128 + t; u < 2303; u += 256) bias_b[u] = bsrc[u];
    }
    const int srow8 = lane >> 3;
    const int gg = (lane & 7) ^ srow8;           // fetch-side granule remap
    const int swz = (l16 & 7) * 8;
    // wave w stages rows w*16 + {0..7} and w*16+8 + {0..7} of each 64-row tile
    const unsigned short* kbase = qkb + (size_t)(b * S_LEN + w * 16 + srow8) * 2048 + 1024 + h * 64 + gg * 8;
    const unsigned short* vbase = vt + (size_t)(b * 1024 + h * 64 + w * 16 + srow8) * 2048 + gg * 8;
    // first K/V tile into buffer 0
    gload16(kbase,                     &Ks[0][(w * 16) * 64]);
    gload16(kbase + (size_t)8 * 2048,  &Ks[0][(w * 16 + 8) * 64]);
    gload16(vbase,                     &Vs[0][(w * 16) * 64]);
    gload16(vbase + (size_t)8 * 2048,  &Vs[0][(w * 16 + 8) * 64]);

    // Q fragments straight from global (Q already log2e-scaled by the GEMM)
    bf16x8 qb[2][2];   // [ks][nt]; wave owns q rows q0 + w*32 + nt*16 + l16
    {
        const unsigned short* qbase =
            qkb + (size_t)(b * S_LEN + q0 + w * 32 + l16) * 2048 + h * 64 + quad * 8;
        for (int nt = 0; nt < 2; nt++)
            for (int ks = 0; ks < 2; ks++)
                qb[ks][nt] = *(const bf16x8*)(qbase + (size_t)nt * 16 * 2048 + ks * 32);
    }
    __syncthreads();   // bias_b + first K/V tile ready

    // ones-row A fragment for the row-sum MFMA: A[m=0][k]=1, rows 1..15 = 0.
    bf16x8 onesA = {};
    if (l16 == 0) {
        const __bf16 one = (__bf16)1.0f;
        for (int e = 0; e < 8; e++) onesA[e] = one;
    }

    f32x4 ctx[4][2] = {};    // ctx^T: [d-tile nd][n-tile nt]
    f32x4 rsacc[2] = {};     // row 0 (quad==0, reg 0) = complete row sum per q
    const int ib0 = 255 + quad * 4 - w * 32 - l16;   // + i*64 - nt*16 + nb*16 + e

    int cur = 0;
    for (int i = 0; i < 32; i++) {
        // prefetch next K/V tile into the other buffer (latency hidden under compute)
        if (i < 31) {
            size_t koff = (size_t)(i + 1) * 64 * 2048;
            gload16(kbase + koff,                    &Ks[cur ^ 1][(w * 16) * 64]);
            gload16(kbase + koff + (size_t)8 * 2048, &Ks[cur ^ 1][(w * 16 + 8) * 64]);
            gload16(vbase + (i + 1) * 64,            &Vs[cur ^ 1][(w * 16) * 64]);
            gload16(vbase + (i + 1) * 64 + (size_t)8 * 2048, &Vs[cur ^ 1][(w * 16 + 8) * 64]);
        }
        // nb-outer pipelined QK^T + softmax: st[nb] = K_nb Q^T + bias (C-init),
        // its exp2/cvt_pk overlap nb+1's MFMAs (no barrier in between).
        const int ibt = ib0 + i * 64;
        uint2 pk[2][4];   // [nt][nb]
        for (int nb = 0; nb < 4; nb++) {
            const int krow = (nb * 16 + l16) * 64;
            bf16x8 ka0 = *(const bf16x8*)&Ks[cur][krow + ((quad * 8) ^ swz)];
            bf16x8 ka1 = *(const bf16x8*)&Ks[cur][krow + (((4 + quad) * 8) ^ swz)];
            const int i0 = ibt + nb * 16;
            f32x4 st0 = {bias_b[i0], bias_b[i0 + 1], bias_b[i0 + 2], bias_b[i0 + 3]};
            f32x4 st1 = {bias_b[i0 - 16], bias_b[i0 - 15], bias_b[i0 - 14], bias_b[i0 - 13]};
            st0 = __builtin_amdgcn_mfma_f32_16x16x32_bf16(ka0, qb[0][0], st0, 0, 0, 0);
            st0 = __builtin_amdgcn_mfma_f32_16x16x32_bf16(ka1, qb[1][0], st0, 0, 0, 0);
            st1 = __builtin_amdgcn_mfma_f32_16x16x32_bf16(ka0, qb[0][1], st1, 0, 0, 0);
            st1 = __builtin_amdgcn_mfma_f32_16x16x32_bf16(ka1, qb[1][1], st1, 0, 0, 0);
            pk[0][nb].x = pkbf(fexp2(st0[0]), fexp2(st0[1]));
            pk[0][nb].y = pkbf(fexp2(st0[2]), fexp2(st0[3]));
            pk[1][nb].x = pkbf(fexp2(st1[0]), fexp2(st1[1]));
            pk[1][nb].y = pkbf(fexp2(st1[2]), fexp2(st1[3]));
        }
        // in-register C-layout -> B-fragment remap (exchange among 4 lanes sharing l16)
        __builtin_amdgcn_s_setprio(1);
        for (int ks = 0; ks < 2; ks++) {
            bf16x8 pbf[2];
            for (int nt = 0; nt < 2; nt++) {
                uint2 x0 = pk[nt][2 * ks], x1 = pk[nt][2 * ks + 1];
                auto sA = __builtin_amdgcn_permlane32_swap(x0.x, x1.x, false, false);
                auto sB = __builtin_amdgcn_permlane16_swap(sA[0], sA[1], false, false);
                auto sC = __builtin_amdgcn_permlane32_swap(x0.y, x1.y, false, false);
                auto sD = __builtin_amdgcn_permlane16_swap(sC[0], sC[1], false, false);
                unsigned int u4[4] = {sB[0], sD[0], sB[1], sD[1]};
                __builtin_memcpy(&pbf[nt], u4, 16);
            }
            rsacc[0] = __builtin_amdgcn_mfma_f32_16x16x32_bf16(onesA, pbf[0], rsacc[0], 0, 0, 0);
            rsacc[1] = __builtin_amdgcn_mfma_f32_16x16x32_bf16(onesA, pbf[1], rsacc[1], 0, 0, 0);
            for (int nd = 0; nd < 4; nd++) {
                bf16x8 va = *(const bf16x8*)&Vs[cur][(nd * 16 + l16) * 64 + (((ks * 4 + quad) * 8) ^ swz)];
                ctx[nd][0] = __builtin_amdgcn_mfma_f32_16x16x32_bf16(va, pbf[0], ctx[nd][0], 0, 0, 0);
                ctx[nd][1] = __builtin_amdgcn_mfma_f32_16x16x32_bf16(va, pbf[1], ctx[nd][1], 0, 0, 0);
            }
        }
        __builtin_amdgcn_s_setprio(0);
        __syncthreads();   // drains prefetch vmcnt (already landed) + guards buffer swap
        cur ^= 1;
    }
    // epilogue: complete row sums in rsacc -> normalize in-register, write FINAL bf16 ctx
    for (int nt = 0; nt < 2; nt++) {
        float rs = __shfl(rsacc[nt][0], l16);   // broadcast rs[q=l16] from quad-0 lane
        float inv = 1.f / rs;
        int row = b * S_LEN + q0 + w * 32 + nt * 16 + l16;
        for (int nd = 0; nd < 4; nd++) {
            uint2 pk2;
            pk2.x = pkbf(ctx[nd][nt][0] * inv, ctx[nd][nt][1] * inv);
            pk2.y = pkbf(ctx[nd][nt][2] * inv, ctx[nd][nt][3] * inv);
            *(uint2*)&ctxb[(size_t)row * 1024 + h * 64 + nd * 16 + quad * 4] = pk2;
        }
    }
}

extern "C" void kernel_launch(void* const* d_in, const int* in_sizes, int n_in,
                              void* d_out, int out_size, void* d_ws, size_t ws_size,
                              hipStream_t stream) {
    const float* hs       = (const float*)d_in[0];
    const float* Wq       = (const float*)d_in[1];
    const float* Wk       = (const float*)d_in[2];
    const float* Wv       = (const float*)d_in[3];
    const float* Wo       = (const float*)d_in[4];
    const float* rel_bias = (const float*)d_in[5];
    float* out = (float*)d_out;

    char* ws = (char*)d_ws;
    float* biasT          = (float*)ws;           ws += 262144;      // 16*4095*4 (+pad)
    unsigned short* hsb   = (unsigned short*)ws;  ws += 8388608;     // 4096x1024 bf16; DEAD after
                                                                     // gemm1 -> reused as ctxb
    unsigned short* WT    = (unsigned short*)ws;  ws += 6291456;     // [Wq^T|Wk^T|Wv^T] 3072x1024
    unsigned short* WoT   = (unsigned short*)ws;  ws += 2097152;     // 1024x1024 bf16
    unsigned short* qkb   = (unsigned short*)ws;  ws += 16777216;    // 4096x2048 bf16 (Q|K)
    unsigned short* Vtg   = (unsigned short*)ws;  ws += 8388608;     // 2048x2048 bf16
    unsigned short* ctxb  = hsb;                  // alias (hsb dead after gemm1)

    prep_kernel<<<dim3(32, 32, 5), 256, 0, stream>>>(
        hs, hsb, Wq, Wk, Wv, Wo,
        WT, WT + 1024 * 1024, WT + 2 * 1024 * 1024, WoT, rel_bias, biasT);

    // Q|K|V projection, BM=64 (1536 blocks = 6/CU); Q|K -> qkb (stride 2048), V -> Vtg
    gemm_bt_kernel<1, 64><<<dim3(24, 64), 256, 0, stream>>>(hsb, WT, nullptr, qkb, Vtg, 1024, 2048);
    // attention, FULL-S (no split): 512 blocks of 256 thr = 2/CU, XCD-swizzled;
    // writes normalized bf16 ctx directly (no partials, no combine)
    flash19_kernel<<<dim3(512), 256, 0, stream>>>(qkb, Vtg, biasT, ctxb);
    // output projection -> fp32 (pure MODE0, gload16 A from ctxb)
    gemm_bt_kernel<0, 64><<<dim3(8, 64), 256, 0, stream>>>(ctxb, WoT, out, nullptr, nullptr, 1024, 1024);
}